// Round 1
// baseline (254.207 us; speedup 1.0000x reference)
//
#include <hip/hip_runtime.h>

// adder2d: out[b,f,l] = -sum_k |W[f,k] - P[b,k,l]|, P = 3x3/s1/p1 im2col of x.
// B=16 C=128 H=W=28 F=128  => M=B*784=12544, N=128, K=1152. fp32 exact.

#define B_   16
#define C_   128
#define HH   28
#define WW   28
#define F_   128
#define L_   (HH * WW)          // 784
#define K_   (C_ * 9)           // 1152
#define BC   8                  // channels per LDS chunk
#define KC   (BC * 9)           // 72 k-steps per chunk
#define NCH  (C_ / BC)          // 16 chunks
#define TM   64                 // l-tile (M)
#define TF   64                 // f-tile (N)
#define LDW  (TF + 4)           // padded LDS row (68 words; 272B = 17*16, keeps b128 aligned)
#define MT_PER_IMG ((L_ + TM - 1) / TM)   // 13

__global__ __launch_bounds__(256, 2)
void adder2d_kernel(const float* __restrict__ x, const float* __restrict__ Wg,
                    float* __restrict__ out) {
    __shared__ __align__(16) float Pl[KC][LDW];   // P tile: [k][m]
    __shared__ __align__(16) float Wl[KC][LDW];   // W tile: [k][f]

    const int t  = threadIdx.x;
    const int tx = t & 15;            // m-thread (fast, for coalesced stores)
    const int ty = t >> 4;            // f-thread
    const int bimg  = blockIdx.x / MT_PER_IMG;
    const int mt    = blockIdx.x - bimg * MT_PER_IMG;
    const int l0    = mt * TM;
    const int f0blk = blockIdx.y * TF;

    // ---- P staging geometry (chunk-independent): element i of this thread is
    // (k_local = (t>>6) + 4*i, m = t&63). Precompute plane offset + channel fold.
    const int mP  = t & 63;
    const int kP0 = t >> 6;
    const int lP  = l0 + mP;
    int poff[18];                      // c_local*784 + y*28 + xw, or -1 if masked
    {
        const int ho = lP / WW, wo = lP - (lP / WW) * WW;
        #pragma unroll
        for (int i = 0; i < 18; ++i) {
            const int kl = kP0 + 4 * i;
            const int cl = kl / 9, r = kl - cl * 9;
            const int kh = r / 3,  kw = r - (r / 3) * 3;
            const int y  = ho + kh - 1, xw = wo + kw - 1;
            const bool v = (lP < L_) && (y >= 0) && (y < HH) && (xw >= 0) && (xw < WW);
            poff[i] = v ? (cl * L_ + y * WW + xw) : -1;
        }
    }
    // ---- W staging geometry: thread t owns f_local = t>>2, k = (t&3) + 4*i.
    const int wF = t >> 2;            // 0..63
    const int wK0 = t & 3;

    const float* xb = x + bimg * (C_ * L_);

    float acc[4][4];
    #pragma unroll
    for (int i = 0; i < 4; ++i)
        #pragma unroll
        for (int j = 0; j < 4; ++j) acc[i][j] = 0.0f;

    for (int ch = 0; ch < NCH; ++ch) {
        const int c8 = ch * BC;
        __syncthreads();
        // stage P: 18 elements/thread, coalesced-ish global reads, conflict-free LDS writes
        const float* xc = xb + c8 * L_;
        #pragma unroll
        for (int i = 0; i < 18; ++i) {
            const int kl = kP0 + 4 * i;
            float v = 0.0f;
            if (poff[i] >= 0) v = xc[poff[i]];
            Pl[kl][mP] = v;
        }
        // stage W: 18 elements/thread; row (f0blk+wF), k = c8*9 + wK0 + 4i
        const float* wrow = Wg + (size_t)(f0blk + wF) * K_ + c8 * 9 + wK0;
        #pragma unroll
        for (int i = 0; i < 18; ++i) {
            Wl[wK0 + 4 * i][wF] = wrow[4 * i];
        }
        __syncthreads();
        // compute: 72 k-steps, 2x ds_read_b128 + 16 sub + 16 add(abs) each
        #pragma unroll 4
        for (int k = 0; k < KC; ++k) {
            const float4 p = *(const float4*)&Pl[k][tx * 4];
            const float4 w = *(const float4*)&Wl[k][ty * 4];
            const float pm[4] = {p.x, p.y, p.z, p.w};
            const float wn[4] = {w.x, w.y, w.z, w.w};
            #pragma unroll
            for (int i = 0; i < 4; ++i)
                #pragma unroll
                for (int j = 0; j < 4; ++j)
                    acc[i][j] += __builtin_fabsf(pm[i] - wn[j]);
        }
    }

    // store: per f (j), float4 across m; 784 % 4 == 0 so mask is all-or-nothing
    const int lbase = l0 + tx * 4;
    if (lbase < L_) {
        #pragma unroll
        for (int j = 0; j < 4; ++j) {
            const int f = f0blk + ty * 4 + j;
            float4 v = make_float4(-acc[0][j], -acc[1][j], -acc[2][j], -acc[3][j]);
            *(float4*)&out[(size_t)(bimg * F_ + f) * L_ + lbase] = v;
        }
    }
}

extern "C" void kernel_launch(void* const* d_in, const int* in_sizes, int n_in,
                              void* d_out, int out_size, void* d_ws, size_t ws_size,
                              hipStream_t stream) {
    const float* x = (const float*)d_in[0];   // [16,128,28,28]
    const float* W = (const float*)d_in[1];   // [128,128,3,3]
    float* out = (float*)d_out;               // [16,128,28,28]

    dim3 grid(B_ * MT_PER_IMG, F_ / TF);      // (208, 2) = 416 blocks
    dim3 block(256);
    adder2d_kernel<<<grid, block, 0, stream>>>(x, W, out);
}

// Round 2
// 205.491 us; speedup vs baseline: 1.2371x; 1.2371x over previous
//
#include <hip/hip_runtime.h>

// adder2d: out[b,f,l] = -sum_k |W[f,k] - P[b,k,l]|, P = 3x3/s1/p1 im2col of x.
// B=16 C=128 H=W=28 F=128  => M=B*784=12544 (flattened, 196 exact 64-tiles),
// N=128, K=1152. fp32 exact. K-split x4 into d_ws + combine kernel.

#define B_   16
#define C_   128
#define HH   28
#define WW   28
#define F_   128
#define L_   (HH * WW)          // 784
#define K_   (C_ * 9)           // 1152
#define M_   (B_ * L_)          // 12544 = 196 * 64 exactly
#define BC   8                  // channels per LDS chunk
#define KC   (BC * 9)           // 72 k-steps per chunk
#define TM   64                 // m-tile
#define TF   64                 // f-tile
#define LDW  (TF + 4)           // padded LDS row: 68 words = 272 B
#define SPLIT 4                 // K-split factor
#define SLAB  (B_ * F_ * L_)    // 1,605,632 floats per partial slab
#define NMT  (M_ / TM)          // 196 m-tiles, exact

__global__ __launch_bounds__(256, 2)
void adder2d_main(const float* __restrict__ x, const float* __restrict__ Wg,
                  float* __restrict__ dst, int nch, int direct) {
    __shared__ __align__(16) float Pl[KC][LDW];
    __shared__ __align__(16) float Wl[KC][LDW];

    const int t  = threadIdx.x;
    const int tx = t & 15;             // m-thread
    const int ty = t >> 4;             // f-thread
    const int m0    = blockIdx.x * TM;
    const int f0blk = blockIdx.y * TF;
    const int c0    = blockIdx.z * nch * BC;   // first channel of this split

    // ---- P staging geometry: thread t stages (k_local = (t>>6)+4i, m = m0 + (t&63)).
    const int mP = t & 63;
    const int kP0 = t >> 6;
    const int mG = m0 + mP;            // global m, always < M_ (exact tiling)
    int poff[18];                      // b*C*L + c_local*L + y*28 + xw, or -1
    {
        const int bI = mG / L_;
        const int lP = mG - bI * L_;
        const int ho = lP / WW, wo = lP - (lP / WW) * WW;
        const int bbase = bI * (C_ * L_);
        #pragma unroll
        for (int i = 0; i < 18; ++i) {
            const int kl = kP0 + 4 * i;
            const int cl = kl / 9, r = kl - cl * 9;
            const int kh = r / 3,  kw = r - (r / 3) * 3;
            const int y  = ho + kh - 1, xw = wo + kw - 1;
            const bool v = (y >= 0) && (y < HH) && (xw >= 0) && (xw < WW);
            poff[i] = v ? (bbase + cl * L_ + y * WW + xw) : -1;
        }
    }
    // ---- W staging geometry: thread t owns f_local = t>>2, k = (t&3)+4i.
    const int wF  = t >> 2;
    const int wK0 = t & 3;

    float acc[4][4];
    #pragma unroll
    for (int i = 0; i < 4; ++i)
        #pragma unroll
        for (int j = 0; j < 4; ++j) acc[i][j] = 0.0f;

    for (int ch = 0; ch < nch; ++ch) {
        const int c8 = c0 + ch * BC;
        __syncthreads();
        const float* xc = x + c8 * L_;
        #pragma unroll
        for (int i = 0; i < 18; ++i) {
            float v = 0.0f;
            if (poff[i] >= 0) v = xc[poff[i]];
            Pl[kP0 + 4 * i][mP] = v;
        }
        const float* wrow = Wg + (size_t)(f0blk + wF) * K_ + c8 * 9 + wK0;
        #pragma unroll
        for (int i = 0; i < 18; ++i) {
            Wl[wK0 + 4 * i][wF] = wrow[4 * i];
        }
        __syncthreads();
        #pragma unroll 8
        for (int k = 0; k < KC; ++k) {
            const float4 p = *(const float4*)&Pl[k][tx * 4];
            const float4 w = *(const float4*)&Wl[k][ty * 4];
            const float pm[4] = {p.x, p.y, p.z, p.w};
            const float wn[4] = {w.x, w.y, w.z, w.w};
            #pragma unroll
            for (int i = 0; i < 4; ++i)
                #pragma unroll
                for (int j = 0; j < 4; ++j)
                    acc[i][j] += __builtin_fabsf(pm[i] - wn[j]);
        }
    }

    // store float4 across m: group [mb, mb+4) never straddles an image (4 | 784).
    const int mb = m0 + tx * 4;
    const int bI = mb / L_;
    const int lb = mb - bI * L_;
    float* slab = direct ? dst : dst + (size_t)blockIdx.z * SLAB;
    const float sgn = direct ? -1.0f : 1.0f;
    #pragma unroll
    for (int j = 0; j < 4; ++j) {
        const int f = f0blk + ty * 4 + j;
        float4 v = make_float4(sgn * acc[0][j], sgn * acc[1][j],
                               sgn * acc[2][j], sgn * acc[3][j]);
        *(float4*)&slab[(size_t)(bI * F_ + f) * L_ + lb] = v;
    }
}

__global__ __launch_bounds__(256)
void adder2d_combine(const float* __restrict__ ws, float* __restrict__ out) {
    const int i = blockIdx.x * 256 + threadIdx.x;     // float4 index, SLAB/4 total
    const float4* a0 = (const float4*)ws;
    const float4* a1 = (const float4*)(ws + SLAB);
    const float4* a2 = (const float4*)(ws + 2 * (size_t)SLAB);
    const float4* a3 = (const float4*)(ws + 3 * (size_t)SLAB);
    float4 p0 = a0[i], p1 = a1[i], p2 = a2[i], p3 = a3[i];
    float4 r;
    r.x = -((p0.x + p1.x) + (p2.x + p3.x));
    r.y = -((p0.y + p1.y) + (p2.y + p3.y));
    r.z = -((p0.z + p1.z) + (p2.z + p3.z));
    r.w = -((p0.w + p1.w) + (p2.w + p3.w));
    ((float4*)out)[i] = r;
}

extern "C" void kernel_launch(void* const* d_in, const int* in_sizes, int n_in,
                              void* d_out, int out_size, void* d_ws, size_t ws_size,
                              hipStream_t stream) {
    const float* x = (const float*)d_in[0];   // [16,128,28,28]
    const float* W = (const float*)d_in[1];   // [128,128,3,3]
    float* out = (float*)d_out;               // [16,128,28,28]
    float* ws  = (float*)d_ws;

    const size_t needed = (size_t)SPLIT * SLAB * sizeof(float);  // ~25.7 MB
    if (ws_size >= needed) {
        dim3 grid(NMT, F_ / TF, SPLIT);       // (196, 2, 4) = 1568 blocks
        adder2d_main<<<grid, 256, 0, stream>>>(x, W, ws, (C_ / BC) / SPLIT, 0);
        adder2d_combine<<<SLAB / 4 / 256, 256, 0, stream>>>(ws, out);
    } else {
        dim3 grid(NMT, F_ / TF, 1);           // fallback: direct, no split
        adder2d_main<<<grid, 256, 0, stream>>>(x, W, out, C_ / BC, 1);
    }
}